// Round 8
// baseline (2163.149 us; speedup 1.0000x reference)
//
#include <hip/hip_runtime.h>
#include <hip/hip_bf16.h>
#include <cstdint>

#define N_NODES 20000
#define N_EDGES 100000
#define WALK 4
#define FDIM 256
#define HID 64
#define NHEAD 8
#define HR 512
#define OUTD 16

typedef __attribute__((ext_vector_type(8))) short bf16x8;
typedef __attribute__((ext_vector_type(8))) unsigned short u16x8;
typedef __attribute__((ext_vector_type(4))) float f32x4;

__device__ __forceinline__ float b2f(unsigned short u){
  union{float f; unsigned u;} x; x.u = ((unsigned)u)<<16; return x.f;
}
__device__ __forceinline__ unsigned short f2b(float f){
  union{float f; unsigned u;} x; x.f = f;
  unsigned r = x.u + 0x7FFFu + ((x.u>>16)&1u);
  return (unsigned short)(r>>16);
}
__device__ __forceinline__ float sigmoidf_(float v){ return 1.0f/(1.0f+__expf(-v)); }
__device__ __forceinline__ float tanh_c(float v){
  v = fminf(fmaxf(v, -15.f), 15.f);
  const float t2 = __expf(2.0f*v);
  return (t2 - 1.0f) / (t2 + 1.0f);
}

__device__ __forceinline__ void gload16(const void* g, void* l){
  __builtin_amdgcn_global_load_lds(
      (const __attribute__((address_space(1))) void*)(g),
      (__attribute__((address_space(3))) void*)(l),
      16, 0, 0);
}

__device__ __forceinline__ f32x4 mfma16(bf16x8 a, bf16x8 b, f32x4 c){
  return __builtin_amdgcn_mfma_f32_16x16x32_bf16(a, b, c, 0, 0, 0);
}

// ---------------- emb = bf16(x @ W_mlp.T + b_mlp)  (20000x64, linear) ----------------
__launch_bounds__(256)
__global__ void emb_kernel(const float* __restrict__ x,
                           const float* __restrict__ Wm,
                           const float* __restrict__ bm,
                           unsigned short* __restrict__ emb_bf)
{
  __shared__ float xs[4][FDIM];
  const int tid = threadIdx.x;
  const int node0 = blockIdx.x * 4;
  {
    const int row = tid >> 6;
    const int k4  = (tid & 63) * 4;
    *reinterpret_cast<float4*>(&xs[row][k4]) =
      *reinterpret_cast<const float4*>(&x[(size_t)(node0+row)*FDIM + k4]);
  }
  __syncthreads();
  const int nn = tid >> 6, c = tid & 63;
  float acc = bm[c];
  const float* wr = &Wm[c*FDIM];
  #pragma unroll 8
  for (int k=0;k<FDIM;k+=4){
    const float4 w = *reinterpret_cast<const float4*>(&wr[k]);
    acc += xs[nn][k]*w.x + xs[nn][k+1]*w.y + xs[nn][k+2]*w.z + xs[nn][k+3]*w.w;
  }
  emb_bf[(size_t)(node0+nn)*HID + c] = f2b(acc);
}

// ---------------- weight prep (bf16, gate-INTERLEAVED frag rows, chunk-swizzle) -------
__launch_bounds__(256)
__global__ void prep_kernel(const float* __restrict__ Whh,
                            const float* __restrict__ Wih,
                            const float* __restrict__ Wemb,
                            unsigned short* __restrict__ WhhP,
                            unsigned short* __restrict__ WihP,
                            unsigned short* __restrict__ WembP)
{
  const int t = blockIdx.x*256 + threadIdx.x;
  if (t < 8*192*512){
    const int k = t & 511;
    const int r = (t >> 9) % 192;
    const int db = t / 98304;
    const int f = r >> 4, fr = r & 15;
    const int g = f % 3, dgrp = f / 3;
    const int G = g*HR + db*64 + dgrp*16 + fr;
    const int kg = k >> 6, kw = k & 63;
    const int c = kw >> 3, o = kw & 7;
    const int ksrc = (kg<<6) + (((c ^ (r&7)) << 3) | o);
    WhhP[t] = f2b(Whh[(size_t)G*HR + ksrc]);
  }
  if (t < 8*192*64){
    const int k = t & 63;
    const int r = (t >> 6) % 192;
    const int db = t / 12288;
    const int f = r >> 4, fr = r & 15;
    const int g = f % 3, dgrp = f / 3;
    const int G = g*HR + db*64 + dgrp*16 + fr;
    const int c = k >> 3, o = k & 7;
    const int ksrc = (((c ^ (r&7)) << 3) | o);
    WihP[t] = f2b(Wih[(size_t)G*HID + ksrc]);
  }
  if (t < 64*512){
    const int k = t & 511;
    const int o = t >> 9;
    const int kg = k >> 6, kw = k & 63;
    const int c = kw >> 3, off = kw & 7;
    const int ksrc = (kg<<6) + (((c ^ (o&7)) << 3) | off);
    WembP[t] = f2b(Wemb[(size_t)o*HR + ksrc]);
  }
}

// ---------------- xg: per-node x-gates -> xgP [node][3][512] (incl b_ih) and h1n ------
__launch_bounds__(512)
__global__ void xg_kernel(const unsigned short* __restrict__ emb_bf,
                          const unsigned short* __restrict__ WihP,
                          const float* __restrict__ b_ih,
                          const float* __restrict__ b_hh,
                          unsigned short* __restrict__ xgP,
                          unsigned short* __restrict__ h1n)
{
  __shared__ __align__(16) char smem[32768 + 24576];
  char* Ab = smem;
  char* Bb = smem + 32768;
  const int tid = threadIdx.x, lane = tid & 63, w = tid >> 6;
  const int wr = w >> 1, wn = w & 1;
  const int n0 = blockIdx.x * 256;
  const int db = blockIdx.y;

  #pragma unroll
  for (int j=0;j<4;++j){
    const int flat = j*512 + tid;
    const int row = flat >> 3, c = flat & 7;
    int n = n0 + row; if (n > N_NODES-1) n = N_NODES-1;
    gload16(emb_bf + ((size_t)n*HID + ((c ^ (row&7))<<3)), Ab + ((j*512 + w*64)<<4));
  }
  #pragma unroll
  for (int j=0;j<3;++j){
    const int flat = j*512 + tid;
    const int row = flat >> 3, c = flat & 7;
    gload16(WihP + ((size_t)(db*192 + row)*HID + c*8), Bb + ((j*512 + w*64)<<4));
  }
  asm volatile("s_waitcnt vmcnt(0)" ::: "memory");
  __builtin_amdgcn_s_barrier();

  f32x4 acc[4][6];
  #pragma unroll
  for (int m=0;m<4;++m)
    #pragma unroll
    for (int f=0;f<6;++f) acc[m][f] = (f32x4)(0.f);

  auto readFrag = [&](const char* base, int row, int kk)->bf16x8{
    const int chunk = (kk<<2) + (lane>>4);
    return *reinterpret_cast<const bf16x8*>(base + (row<<7) + ((chunk ^ (row&7))<<4));
  };
  #pragma unroll
  for (int kk=0; kk<2; ++kk){
    bf16x8 a_[4];
    #pragma unroll
    for (int mf=0; mf<4; ++mf) a_[mf] = readFrag(Ab, wr*64 + mf*16 + (lane&15), kk);
    #pragma unroll
    for (int nf=0; nf<6; ++nf){
      const bf16x8 b_ = readFrag(Bb, wn*96 + nf*16 + (lane&15), kk);
      #pragma unroll
      for (int mf=0; mf<4; ++mf) acc[mf][nf] = mfma16(a_[mf], b_, acc[mf][nf]);
    }
  }

  const int fr_ = lane & 15;
  #pragma unroll
  for (int mf=0; mf<4; ++mf){
    #pragma unroll
    for (int reg=0; reg<4; ++reg){
      const int row = wr*64 + mf*16 + ((lane>>4)<<2) + reg;
      const int n = n0 + row;
      if (n < N_NODES){
        #pragma unroll
        for (int t=0; t<2; ++t){
          const int d6 = (2*wn+t)*16 + fr_;
          const int dG = db*64 + d6;
          const float xr = acc[mf][t*3+0][reg] + b_ih[dG];
          const float xz = acc[mf][t*3+1][reg] + b_ih[HR+dG];
          const float xn = acc[mf][t*3+2][reg] + b_ih[2*HR+dG];
          xgP[(size_t)n*1536 + dG]        = f2b(xr);
          xgP[(size_t)n*1536 + 512 + dG]  = f2b(xz);
          xgP[(size_t)n*1536 + 1024 + dG] = f2b(xn);
          const float r = sigmoidf_(xr + b_hh[dG]);
          const float z = sigmoidf_(xz + b_hh[HR+dG]);
          const float nn = tanh_c(xn + r*b_hh[2*HR+dG]);
          h1n[(size_t)n*HR + dG] = f2b((1.0f - z)*nn);
        }
      }
    }
  }
}

// ---------------- FUSED GRU: steps 1..3 with h resident in LDS ----------------
// 64 edges/block, 512 thr / 8 waves: rg=w>>2 (32-row half), dgrp=w&3 (16-col gate-triple).
// h LDS [64][512] bf16 chunk-swizzled (64KB). B tri-buffer 3x24KB from L2 (counted vmcnt).
// Per (t,db): 8 K-tiles of pure-B staging + MFMA (mf=2, nf=3 gates); epilogue fuses gates
// with gathered per-node x-gates (xgP) and writes h_new to a 64-reg stash; committed to
// LDS once per step. hT written to HBM once at the end. h NEVER round-trips HBM.
__launch_bounds__(512, 2)
__global__ void gru_fused(const int* __restrict__ idx,
                          const unsigned short* __restrict__ h1n,
                          const unsigned short* __restrict__ WhhP,
                          const unsigned short* __restrict__ xgP,
                          const float* __restrict__ b_hh,
                          const float* __restrict__ attn,
                          unsigned short* __restrict__ hT,
                          float* __restrict__ a_buf)
{
  __shared__ __align__(16) char smem[147456];
  char* const hL = smem;                                   // 64KB
  float* const biasT = (float*)(smem + 139264);            // [3][512] f32
  float* const attnT = (float*)(smem + 145408);            // [512] f32

  const int tid = threadIdx.x, lane = tid & 63, w = tid >> 6;
  const int lrow = lane & 15, lkg = lane >> 4;
  const int rg = w >> 2, dgrp = w & 3;
  const int e0 = blockIdx.x * 64;

  auto Bbuf = [&](int s)->char*{ return smem + 65536 + s*24576; };

  // bias + attn tables
  biasT[tid]      = b_hh[tid];
  biasT[512+tid]  = b_hh[HR+tid];
  biasT[1024+tid] = b_hh[2*HR+tid];
  attnT[tid]      = attn[tid];

  // h1 gather -> hL (chunk-swizzled rows)
  #pragma unroll
  for (int j=0;j<8;++j){
    const int flat = j*512 + tid;
    const int row = flat >> 6, c64 = flat & 63;
    int e = e0 + row; if (e > N_EDGES-1) e = N_EDGES-1;
    const int n0 = idx[e*WALK];
    const u16x8 v = *reinterpret_cast<const u16x8*>(h1n + (size_t)n0*HR + c64*8);
    *reinterpret_cast<u16x8*>(hL + row*1024 + (c64>>3)*128 + (((c64&7) ^ (row&7))<<4)) = v;
  }
  __syncthreads();

  auto readA = [&](int row, int kt, int kk)->bf16x8{
    return *reinterpret_cast<const bf16x8*>(
        hL + row*1024 + kt*128 + (((lkg + kk*4) ^ (row&7))<<4));
  };
  auto readB = [&](const char* bb, int r, int kk)->bf16x8{
    return *reinterpret_cast<const bf16x8*>(
        bb + r*128 + (((lkg + kk*4) ^ (r&7))<<4));
  };
  auto stageB = [&](int slot, int db, int kt){
    #pragma unroll
    for (int j=0;j<3;++j){
      const int flat = j*512 + tid;
      const int r = flat >> 3, c = flat & 7;
      gload16(WhhP + ((size_t)(db*192 + r)*HR + kt*64 + c*8),
              Bbuf(slot) + ((j*512 + w*64) << 4));
    }
  };

  float hsv[8][8];   // [db][mf*4+reg] h_new stash (static indexing only)

  #pragma unroll 1
  for (int t=1; t<WALK; ++t){
    // per-lane edge nodes for this step's x-gates
    int nodes[2][4];
    #pragma unroll
    for (int mf=0;mf<2;++mf)
      #pragma unroll
      for (int reg=0;reg<4;++reg){
        int e = e0 + rg*32 + mf*16 + lkg*4 + reg;
        if (e > N_EDGES-1) e = N_EDGES-1;
        nodes[mf][reg] = idx[e*WALK + t];
      }

    #pragma unroll
    for (int db=0; db<8; ++db){
      f32x4 acc[2][3];
      #pragma unroll
      for (int m=0;m<2;++m)
        #pragma unroll
        for (int g=0;g<3;++g) acc[m][g] = (f32x4)(0.f);

      stageB(0, db, 0); stageB(1, db, 1);

      #pragma unroll 1
      for (int kt=0; kt<8; ++kt){
        if (kt == 7) asm volatile("s_waitcnt vmcnt(0)" ::: "memory");
        else         asm volatile("s_waitcnt vmcnt(3)" ::: "memory");
        __builtin_amdgcn_s_barrier();
        __builtin_amdgcn_sched_barrier(0);
        if (kt + 2 < 8) stageB((kt+2)%3, db, kt+2);
        char* bb = Bbuf(kt%3);
        #pragma unroll
        for (int kk=0; kk<2; ++kk){
          const bf16x8 a0 = readA(rg*32 + lrow,      kt, kk);
          const bf16x8 a1 = readA(rg*32 + 16 + lrow, kt, kk);
          __builtin_amdgcn_s_setprio(1);
          #pragma unroll
          for (int g=0; g<3; ++g){
            const bf16x8 b_ = readB(bb, (dgrp*3+g)*16 + lrow, kk);
            acc[0][g] = mfma16(a0, b_, acc[0][g]);
            acc[1][g] = mfma16(a1, b_, acc[1][g]);
          }
          __builtin_amdgcn_s_setprio(0);
        }
      }
      __builtin_amdgcn_s_barrier();   // all compute(7) done before next db's staging

      // ---- epilogue (register-local): gates + h_new stash ----
      const int col = db*64 + dgrp*16 + lrow;
      const float br = biasT[col], bz = biasT[512+col], bn = biasT[1024+col];
      const float av = attnT[col];
      #pragma unroll
      for (int mf=0;mf<2;++mf){
        #pragma unroll
        for (int reg=0;reg<4;++reg){
          const int row = rg*32 + mf*16 + lkg*4 + reg;
          const int node = nodes[mf][reg];
          const size_t xb = (size_t)node*1536 + col;
          const float xr = b2f(xgP[xb]);
          const float xz = b2f(xgP[xb + 512]);
          const float xn = b2f(xgP[xb + 1024]);
          const float hold = b2f(*reinterpret_cast<const unsigned short*>(
              hL + row*1024 + db*128 + ((((col>>3)&7) ^ (row&7))<<4) + (col&7)*2));
          const float r  = sigmoidf_(xr + acc[mf][0][reg] + br);
          const float z  = sigmoidf_(xz + acc[mf][1][reg] + bz);
          const float nn = tanh_c(xn + r*(acc[mf][2][reg] + bn));
          const float hv = (1.0f - z)*nn + z*hold;
          hsv[db][mf*4+reg] = hv;
          if (t == WALK-1){
            float s = hv * av;
            s += __shfl_xor(s, 1);
            s += __shfl_xor(s, 2);
            s += __shfl_xor(s, 4);
            s += __shfl_xor(s, 8);
            const int e = e0 + row;
            if (lrow == mf*4+reg && e < N_EDGES)
              atomicAdd(&a_buf[e*NHEAD + db], s);
          }
        }
      }
    } // db

    // ---- commit h_new stash -> hL ----
    __syncthreads();
    #pragma unroll
    for (int db=0; db<8; ++db){
      const int col = db*64 + dgrp*16 + lrow;
      #pragma unroll
      for (int mf=0;mf<2;++mf)
        #pragma unroll
        for (int reg=0;reg<4;++reg){
          const int row = rg*32 + mf*16 + lkg*4 + reg;
          *reinterpret_cast<unsigned short*>(
              hL + row*1024 + db*128 + ((((col>>3)&7) ^ (row&7))<<4) + (col&7)*2)
            = f2b(hsv[db][mf*4+reg]);
        }
    }
    __syncthreads();
  } // t

  // ---- hT copy (LDS raw -> global raw; layout == per-row chunk-swizzle) ----
  #pragma unroll
  for (int j=0;j<8;++j){
    const int flat = j*512 + tid;
    const int row = flat >> 6;
    const int e = e0 + row;
    if (e < N_EDGES){
      const u16x8 v = *reinterpret_cast<const u16x8*>(hL + flat*16);
      *reinterpret_cast<u16x8*>(hT + (size_t)e*HR + (flat&63)*8) = v;
    }
  }
}

// ---------------- score finalize: leaky-relu + segment max ----------------
__launch_bounds__(256)
__global__ void score2_kernel(const int* __restrict__ idx,
                              float* __restrict__ a_buf,
                              unsigned int* __restrict__ mmax)
{
  const int flat = blockIdx.x*256 + threadIdx.x;
  const int e = flat >> 3, h = flat & 7;
  const float s = a_buf[flat];
  const float a = s > 0.f ? s : 0.01f*s;
  a_buf[flat] = a;
  const int dst = idx[e*WALK + 3];
  union{float f; unsigned u;} x; x.f = a;
  const unsigned key = (x.u & 0x80000000u) ? ~x.u : (x.u | 0x80000000u);
  atomicMax(&mmax[dst*NHEAD + h], key);
}

// ---------------- exp(a-m) + segment sum ----------------
__launch_bounds__(256)
__global__ void ea_kernel(const int* __restrict__ idx,
                          float* __restrict__ a_buf,
                          const unsigned int* __restrict__ mmax,
                          float* __restrict__ ssum)
{
  const int flat = blockIdx.x*256 + threadIdx.x;
  const int e = flat >> 3, h = flat & 7;
  const int dst = idx[e*WALK + 3];
  const unsigned key = mmax[dst*NHEAD + h];
  union{float f; unsigned u;} x;
  x.u = (key & 0x80000000u) ? (key & 0x7FFFFFFFu) : ~key;
  const float ea = __expf(a_buf[flat] - x.f);
  a_buf[flat] = ea;
  atomicAdd(&ssum[dst*NHEAD + h], ea);
}

// ---------------- alpha = ea / ssum[dst]  (in place) ----------------
__launch_bounds__(256)
__global__ void alpha_kernel(const int* __restrict__ idx,
                             float* __restrict__ a_buf,
                             const float* __restrict__ ssum)
{
  const int flat = blockIdx.x*256 + threadIdx.x;
  const int e = flat >> 3, h = flat & 7;
  const int dst = idx[e*WALK + 3];
  a_buf[flat] = a_buf[flat] / ssum[dst*NHEAD + h];
}

// ---------------- z[e] = (hT[e]*alpha) @ Wemb.T ; zacc[dst] += z[e] ----------------
__launch_bounds__(256)
__global__ void z_kernel(const unsigned short* __restrict__ hT,
                         const int* __restrict__ idx,
                         const float* __restrict__ alpha,
                         const unsigned short* __restrict__ WembP,
                         float* __restrict__ zacc)
{
  __shared__ __align__(16) char zs[40960];  // Az 32768 + Bz 8192
  char* Az = zs;
  char* Bz = zs + 32768;
  const int tid = threadIdx.x;
  const int lane = tid & 63;
  const int w = tid >> 6;
  const int e0 = blockIdx.x * 256;

  f32x4 acc[4][4];
  #pragma unroll
  for (int m=0;m<4;++m)
    #pragma unroll
    for (int f=0;f<4;++f) acc[m][f] = (f32x4)(0.f);

  auto readFrag = [&](const char* base, int row, int kk)->bf16x8{
    const int chunk = (kk<<2) + (lane>>4);
    return *reinterpret_cast<const bf16x8*>(base + (row<<7) + ((chunk ^ (row&7))<<4));
  };

  #pragma unroll 1
  for (int kt=0; kt<8; ++kt){
    __syncthreads();
    #pragma unroll
    for (int j=0;j<8;++j){
      const int flat = j*256 + tid;
      const int row = flat >> 3, c = flat & 7;
      int e = e0 + row; if (e > N_EDGES-1) e = N_EDGES-1;
      const u16x8 hv = *reinterpret_cast<const u16x8*>(hT + (size_t)e*HR + kt*64 + c*8);
      const float al = alpha[e*NHEAD + kt];
      union { bf16x8 v; unsigned short s[8]; } o;
      #pragma unroll
      for (int i=0;i<8;++i) o.s[i] = f2b(b2f(hv[i]) * al);
      *reinterpret_cast<bf16x8*>(Az + flat*16) = o.v;
    }
    #pragma unroll
    for (int j=0;j<2;++j){
      const int flat = j*256 + tid;
      const int row = flat >> 3, c = flat & 7;
      gload16(WembP + ((size_t)row*HR + kt*64 + c*8), Bz + ((j*256 + w*64)<<4));
    }
    __syncthreads();
    #pragma unroll
    for (int kk=0; kk<2; ++kk){
      bf16x8 a_[4];
      #pragma unroll
      for (int mf=0; mf<4; ++mf)
        a_[mf] = readFrag(Az, w*64 + mf*16 + (lane&15), kk);
      #pragma unroll
      for (int nf=0; nf<4; ++nf){
        const bf16x8 b_ = readFrag(Bz, nf*16 + (lane&15), kk);
        #pragma unroll
        for (int mf=0; mf<4; ++mf)
          acc[mf][nf] = mfma16(a_[mf], b_, acc[mf][nf]);
      }
    }
  }

  #pragma unroll
  for (int mf=0; mf<4; ++mf){
    #pragma unroll
    for (int reg=0; reg<4; ++reg){
      const int row = w*64 + mf*16 + ((lane>>4)<<2) + reg;
      const int e = e0 + row;
      if (e < N_EDGES){
        const int dst = idx[e*WALK + 3];
        #pragma unroll
        for (int nf=0; nf<4; ++nf){
          const int o = nf*16 + (lane&15);
          atomicAdd(&zacc[(size_t)dst*64 + o], acc[mf][nf][reg]);
        }
      }
    }
  }
}

// ---------------- out = (zacc + b_emb) @ W_last.T + b_last ----------------
__launch_bounds__(256)
__global__ void out2_kernel(const float* __restrict__ zacc,
                            const float* __restrict__ b_emb,
                            const float* __restrict__ W_last,
                            const float* __restrict__ b_last,
                            float* __restrict__ out)
{
  const int flat = blockIdx.x*256 + threadIdx.x;
  if (flat >= N_NODES*OUTD) return;
  const int n = flat >> 4, o = flat & 15;
  float s = b_last[o];
  const float* zr = &zacc[(size_t)n*64];
  const float* wl = &W_last[o*64];
  #pragma unroll
  for (int k=0;k<64;++k) s += (zr[k] + b_emb[k]) * wl[k];
  out[(size_t)n*OUTD + o] = s;
}

// ---------------- launch ----------------
extern "C" void kernel_launch(void* const* d_in, const int* in_sizes, int n_in,
                              void* d_out, int out_size, void* d_ws, size_t ws_size,
                              hipStream_t stream)
{
  (void)in_sizes; (void)n_in; (void)out_size; (void)ws_size;
  const float* x      = (const float*)d_in[0];
  const float* W_mlp  = (const float*)d_in[1];
  const float* b_mlp  = (const float*)d_in[2];
  const float* W_ih   = (const float*)d_in[3];
  const float* W_hh   = (const float*)d_in[4];
  const float* b_ih   = (const float*)d_in[5];
  const float* b_hh   = (const float*)d_in[6];
  const float* attn   = (const float*)d_in[7];
  const float* W_emb  = (const float*)d_in[8];
  const float* b_emb  = (const float*)d_in[9];
  const float* W_last = (const float*)d_in[10];
  const float* b_last = (const float*)d_in[11];
  const int*   idx    = (const int*)d_in[12];
  float* out = (float*)d_out;

  char* ws = (char*)d_ws;
  unsigned short* WhhP   = (unsigned short*)(ws + 0);            //   1,572,864
  unsigned short* WihP   = (unsigned short*)(ws + 1572864);      //     196,608
  unsigned short* WembP  = (unsigned short*)(ws + 1769472);      //      65,536
  unsigned short* emb_bf = (unsigned short*)(ws + 1835008);      //   2,560,000
  unsigned short* h1n    = (unsigned short*)(ws + 4395008);      //  20,480,000
  unsigned short* xgP    = (unsigned short*)(ws + 24875008);     //  61,440,000
  float*          a_buf  = (float*)(ws + 86315008);              //   3,200,000
  unsigned int*   mmax   = (unsigned int*)(ws + 89515008);       //     640,000
  float*          ssum   = (float*)(ws + 90155008);              //     640,000
  float*          zacc   = (float*)(ws + 90795008);              //   5,120,000
  unsigned short* hT     = (unsigned short*)(ws + 95915008);     // 102,400,000
  // total = 198,315,008 B

  // zero a_buf + mmax + ssum + zacc (contiguous 9.6 MB)
  hipMemsetAsync(a_buf, 0, 9600000, stream);

  prep_kernel<<<3072, 256, 0, stream>>>(W_hh, W_ih, W_emb, WhhP, WihP, WembP);
  emb_kernel<<<N_NODES/4, 256, 0, stream>>>(x, W_mlp, b_mlp, emb_bf);

  dim3 xgrid(79, 8);
  xg_kernel<<<xgrid, 512, 0, stream>>>(emb_bf, WihP, b_ih, b_hh, xgP, h1n);

  const int NB = (N_EDGES + 63) / 64;   // 1563
  gru_fused<<<NB, 512, 0, stream>>>(idx, h1n, WhhP, xgP, b_hh, attn, hT, a_buf);

  score2_kernel<<<N_EDGES*NHEAD/256, 256, 0, stream>>>(idx, a_buf, mmax);
  ea_kernel<<<N_EDGES*NHEAD/256, 256, 0, stream>>>(idx, a_buf, mmax, ssum);
  alpha_kernel<<<N_EDGES*NHEAD/256, 256, 0, stream>>>(idx, a_buf, ssum);
  z_kernel<<<391, 256, 0, stream>>>(hT, idx, a_buf, WembP, zacc);
  out2_kernel<<<(N_NODES*OUTD+255)/256, 256, 0, stream>>>(zacc, b_emb, W_last, b_last, out);
}

// Round 9
// 1184.371 us; speedup vs baseline: 1.8264x; 1.8264x over previous
//
#include <hip/hip_runtime.h>
#include <hip/hip_bf16.h>
#include <cstdint>

#define N_NODES 20000
#define N_EDGES 100000
#define WALK 4
#define FDIM 256
#define HID 64
#define NHEAD 8
#define HR 512
#define OUTD 16

typedef __attribute__((ext_vector_type(8))) short bf16x8;
typedef __attribute__((ext_vector_type(8))) unsigned short u16x8;
typedef __attribute__((ext_vector_type(4))) float f32x4;

__device__ __forceinline__ float b2f(unsigned short u){
  union{float f; unsigned u;} x; x.u = ((unsigned)u)<<16; return x.f;
}
__device__ __forceinline__ unsigned short f2b(float f){
  union{float f; unsigned u;} x; x.f = f;
  unsigned r = x.u + 0x7FFFu + ((x.u>>16)&1u);
  return (unsigned short)(r>>16);
}
__device__ __forceinline__ float sigmoidf_(float v){ return 1.0f/(1.0f+__expf(-v)); }
__device__ __forceinline__ float tanh_c(float v){
  v = fminf(fmaxf(v, -15.f), 15.f);
  const float t2 = __expf(2.0f*v);
  return (t2 - 1.0f) / (t2 + 1.0f);
}

__device__ __forceinline__ void gload16(const void* g, void* l){
  __builtin_amdgcn_global_load_lds(
      (const __attribute__((address_space(1))) void*)(g),
      (__attribute__((address_space(3))) void*)(l),
      16, 0, 0);
}

__device__ __forceinline__ f32x4 mfma16(bf16x8 a, bf16x8 b, f32x4 c){
  return __builtin_amdgcn_mfma_f32_16x16x32_bf16(a, b, c, 0, 0, 0);
}

// ---------------- emb = bf16(x @ W_mlp.T + b_mlp)  (20000x64, linear) ----------------
__launch_bounds__(256)
__global__ void emb_kernel(const float* __restrict__ x,
                           const float* __restrict__ Wm,
                           const float* __restrict__ bm,
                           unsigned short* __restrict__ emb_bf)
{
  __shared__ float xs[4][FDIM];
  const int tid = threadIdx.x;
  const int node0 = blockIdx.x * 4;
  {
    const int row = tid >> 6;
    const int k4  = (tid & 63) * 4;
    *reinterpret_cast<float4*>(&xs[row][k4]) =
      *reinterpret_cast<const float4*>(&x[(size_t)(node0+row)*FDIM + k4]);
  }
  __syncthreads();
  const int nn = tid >> 6, c = tid & 63;
  float acc = bm[c];
  const float* wr = &Wm[c*FDIM];
  #pragma unroll 8
  for (int k=0;k<FDIM;k+=4){
    const float4 w = *reinterpret_cast<const float4*>(&wr[k]);
    acc += xs[nn][k]*w.x + xs[nn][k+1]*w.y + xs[nn][k+2]*w.z + xs[nn][k+3]*w.w;
  }
  emb_bf[(size_t)(node0+nn)*HID + c] = f2b(acc);
}

// ---------------- weight prep (bf16, gate-BLOCKED rows, chunk-swizzle) ----------------
// WhhP: [8 db][192 r][512 k]; row r -> W row G=(r>>6)*512 + db*64 + (r&63);
// position chunk c holds logical chunk c^(r&7) per 64-k group. WihP: [8][192][64] same.
// WembP: [64 o][512 k] keyed by o&7.
__launch_bounds__(256)
__global__ void prep_kernel(const float* __restrict__ Whh,
                            const float* __restrict__ Wih,
                            const float* __restrict__ Wemb,
                            unsigned short* __restrict__ WhhP,
                            unsigned short* __restrict__ WihP,
                            unsigned short* __restrict__ WembP)
{
  const int t = blockIdx.x*256 + threadIdx.x;
  if (t < 8*192*512){
    const int k = t & 511;
    const int r = (t >> 9) % 192;
    const int db = t / 98304;
    const int G = (r>>6)*HR + db*64 + (r&63);
    const int kg = k >> 6, kw = k & 63;
    const int c = kw >> 3, o = kw & 7;
    const int ksrc = (kg<<6) + (((c ^ (r&7)) << 3) | o);
    WhhP[t] = f2b(Whh[(size_t)G*HR + ksrc]);
  }
  if (t < 8*192*64){
    const int k = t & 63;
    const int r = (t >> 6) % 192;
    const int db = t / 12288;
    const int G = (r>>6)*HR + db*64 + (r&63);
    const int c = k >> 3, o = k & 7;
    const int ksrc = (((c ^ (r&7)) << 3) | o);
    WihP[t] = f2b(Wih[(size_t)G*HID + ksrc]);
  }
  if (t < 64*512){
    const int k = t & 511;
    const int o = t >> 9;
    const int kg = k >> 6, kw = k & 63;
    const int c = kw >> 3, off = kw & 7;
    const int ksrc = (kg<<6) + (((c ^ (o&7)) << 3) | off);
    WembP[t] = f2b(Wemb[(size_t)o*HR + ksrc]);
  }
}

// ---------------- xg: per-node x-gates -> xnP (n-gate + b_ih_n) and h1n ---------------
// Same 4-wave 128x192 tile as gru, K=64 single tile, gate-blocked B.
__launch_bounds__(256)
__global__ void xg_kernel(const unsigned short* __restrict__ emb_bf,
                          const unsigned short* __restrict__ WihP,
                          const float* __restrict__ b_ih,
                          const float* __restrict__ b_hh,
                          unsigned short* __restrict__ xnP,
                          unsigned short* __restrict__ h1n)
{
  __shared__ __align__(16) unsigned short As[128*64];
  __shared__ __align__(16) unsigned short Bs[192*64];
  const int tid = threadIdx.x, lane = tid & 63, w = tid >> 6;
  const int tx = lane & 15, ty = lane >> 4;
  const int n0 = blockIdx.x * 128;
  const int db = blockIdx.y;

  #pragma unroll
  for (int j=0;j<4;++j){
    const int flat = j*256 + tid;
    const int row = flat >> 3, c = flat & 7;
    int n = n0 + row; if (n > N_NODES-1) n = N_NODES-1;
    gload16(emb_bf + ((size_t)n*HID + ((c ^ (row&7))<<3)), (char*)As + flat*16);
  }
  #pragma unroll
  for (int j=0;j<6;++j){
    const int flat = j*256 + tid;
    const int row = flat >> 3, c = flat & 7;
    gload16(WihP + ((size_t)(db*192 + row)*HID + c*8), (char*)Bs + flat*16);
  }
  __syncthreads();

  f32x4 acc[2][12];
  #pragma unroll
  for (int m=0;m<2;++m)
    #pragma unroll
    for (int f=0;f<12;++f) acc[m][f] = (f32x4)(0.f);

  auto readFrag = [&](const unsigned short* base, int row, int kk)->bf16x8{
    const int chunk = (kk<<2) + ty;
    return *reinterpret_cast<const bf16x8*>(
        reinterpret_cast<const char*>(base) + (row<<7) + ((chunk ^ (row&7))<<4));
  };
  #pragma unroll
  for (int kk=0; kk<2; ++kk){
    const bf16x8 a0 = readFrag(As, w*32 + tx, kk);
    const bf16x8 a1 = readFrag(As, w*32 + 16 + tx, kk);
    #pragma unroll
    for (int nf=0; nf<12; ++nf){
      const bf16x8 b = readFrag(Bs, nf*16 + tx, kk);
      acc[0][nf] = mfma16(a0, b, acc[0][nf]);
      acc[1][nf] = mfma16(a1, b, acc[1][nf]);
    }
  }

  #pragma unroll
  for (int m=0;m<2;++m){
    #pragma unroll
    for (int reg=0; reg<4; ++reg){
      const int row = w*32 + m*16 + ty*4 + reg;
      const int n = n0 + row;
      if (n < N_NODES){
        #pragma unroll
        for (int fr=0; fr<4; ++fr){
          const int d6 = fr*16 + tx;
          const int dG = db*64 + d6;
          const float xr = acc[m][fr][reg]   + b_ih[dG];
          const float xz = acc[m][4+fr][reg] + b_ih[HR+dG];
          const float xn = acc[m][8+fr][reg] + b_ih[2*HR+dG];
          xnP[((size_t)db*N_NODES + n)*64 + d6] = f2b(xn);
          const float r = sigmoidf_(xr + b_hh[dG]);
          const float z = sigmoidf_(xz + b_hh[HR+dG]);
          const float nn = tanh_c(xn + r*b_hh[2*HR+dG]);
          h1n[(size_t)n*HR + dG] = f2b((1.0f - z)*nn);
        }
      }
    }
  }
}

// ---------------- GRU step via MFMA: R2 core (4 waves, 40KB, 2-barrier) ---------------
// BM=128 edges, BN=192 (gate-blocked: nf 0..3=r, 4..7=z, 8..11=n), BK=64.
// kt 0..7 = h (K=512), kt 8 = x (gathered emb; n-frags skipped, xn from xnP).
// Wave w owns rows [w*32,+32) (2 Mf), all 12 Nf. acc[2][12] = 96 VGPR.
// 3-4 blocks/CU co-resident hide the per-kt staging drain (m114 overlap).
template<int STEP, bool SCORE>
__launch_bounds__(256)
__global__ void gru_mfma(const unsigned short* __restrict__ emb_bf,
                         const int* __restrict__ idx,
                         const unsigned short* __restrict__ h_in,  // STEP==1: h1n per-node linear; else per-edge swizzled
                         unsigned short* __restrict__ h_out,
                         const unsigned short* __restrict__ WhhP,
                         const unsigned short* __restrict__ WihP,
                         const unsigned short* __restrict__ xnP,
                         const float* __restrict__ b_ih,
                         const float* __restrict__ b_hh,
                         const float* __restrict__ attn,
                         float* __restrict__ a_buf)
{
  constexpr bool GATHER = (STEP == 1);
  __shared__ __align__(16) unsigned short As[128*64];   // 16 KB
  __shared__ __align__(16) unsigned short Bs[192*64];   // 24 KB

  const int tid = threadIdx.x, lane = tid & 63, w = tid >> 6;
  const int tx = lane & 15, ty = lane >> 4;

  const int bid = blockIdx.x;
  const int sid = (bid & 7)*782 + (bid >> 3);   // bijective XCD swizzle (6256 = 8*782)
  const int et = sid >> 3;
  const int db = sid & 7;
  const int e0 = et * 128;

  // preload idx-derived nodes (no vmem address work inside the K-loop)
  int eS[4], nH[4], nX[4];
  #pragma unroll
  for (int j=0;j<4;++j){
    int e = e0 + ((j*256 + tid) >> 3);
    if (e > N_EDGES-1) e = N_EDGES-1;
    eS[j] = e;
    nX[j] = idx[e*WALK + STEP];
    nH[j] = GATHER ? idx[e*WALK] : 0;
  }

  f32x4 acc[2][12];
  #pragma unroll
  for (int m=0;m<2;++m)
    #pragma unroll
    for (int f=0;f<12;++f) acc[m][f] = (f32x4)(0.f);

  auto stageA = [&](int kt){
    #pragma unroll
    for (int j=0;j<4;++j){
      const int flat = j*256 + tid;
      const int row = flat >> 3, c = flat & 7;
      const unsigned short* src;
      if (kt == 8){
        src = emb_bf + ((size_t)nX[j]*HID + ((c ^ (row&7)) << 3));
      } else if (GATHER){
        src = h_in + ((size_t)nH[j]*HR + kt*64 + ((c ^ (row&7)) << 3));
      } else {
        src = h_in + ((size_t)eS[j]*HR + kt*64 + c*8);
      }
      gload16(src, (char*)As + flat*16);
    }
  };
  auto stageB = [&](int kt){
    #pragma unroll
    for (int j=0;j<6;++j){
      const int flat = j*256 + tid;
      const int row = flat >> 3, c = flat & 7;
      const unsigned short* src = (kt < 8)
        ? WhhP + ((size_t)(db*192 + row)*HR + kt*64 + c*8)
        : WihP + ((size_t)(db*192 + row)*HID + c*8);
      gload16(src, (char*)Bs + flat*16);
    }
  };
  auto readFrag = [&](const unsigned short* base, int row, int kk)->bf16x8{
    const int chunk = (kk<<2) + ty;
    return *reinterpret_cast<const bf16x8*>(
        reinterpret_cast<const char*>(base) + (row<<7) + ((chunk ^ (row&7))<<4));
  };

  stageA(0); stageB(0);

  #pragma unroll
  for (int kt=0; kt<9; ++kt){
    __syncthreads();            // drains vmcnt for the staged tile (compiler-inserted)
    #pragma unroll
    for (int kk=0; kk<2; ++kk){
      const bf16x8 a0 = readFrag(As, w*32 + tx, kk);
      const bf16x8 a1 = readFrag(As, w*32 + 16 + tx, kk);
      #pragma unroll
      for (int nf=0; nf<12; ++nf){
        if (kt == 8 && nf >= 8) continue;     // x-tile: skip n-gate (xn comes from xnP)
        const bf16x8 b = readFrag(Bs, nf*16 + tx, kk);
        acc[0][nf] = mfma16(a0, b, acc[0][nf]);
        acc[1][nf] = mfma16(a1, b, acc[1][nf]);
      }
    }
    if (kt < 8){
      __syncthreads();
      stageA(kt+1); stageB(kt+1);
    }
  }

  // ---- epilogue: pure-register gate fusion (wave owns full r,z,n triples) ----
  float bir[4], biz[4], bhn[4], atv[4];
  #pragma unroll
  for (int fr=0; fr<4; ++fr){
    const int dG = db*64 + fr*16 + tx;
    bir[fr] = b_ih[dG]      + b_hh[dG];
    biz[fr] = b_ih[HR+dG]   + b_hh[HR+dG];
    bhn[fr] = b_hh[2*HR+dG];
    atv[fr] = SCORE ? attn[dG] : 0.f;
  }

  #pragma unroll
  for (int m=0;m<2;++m){
    #pragma unroll
    for (int reg=0; reg<4; ++reg){
      const int row = w*32 + m*16 + ty*4 + reg;
      const int e = e0 + row;
      float sp = 0.f;
      if (e < N_EDGES){
        const int nodeS = idx[e*WALK + STEP];
        const int nodeH = GATHER ? idx[e*WALK] : 0;
        #pragma unroll
        for (int fr=0; fr<4; ++fr){
          const int d6 = fr*16 + tx;
          const int dG = db*64 + d6;
          const float xn = b2f(xnP[((size_t)db*N_NODES + nodeS)*64 + d6]);
          float hold;
          if (GATHER) hold = b2f(h_in[(size_t)nodeH*HR + dG]);
          else        hold = b2f(h_in[(size_t)e*HR + db*64 + (((d6>>3) ^ (e&7))<<3) + (d6&7)]);
          const float r  = sigmoidf_(acc[m][fr][reg]   + bir[fr]);
          const float z  = sigmoidf_(acc[m][4+fr][reg] + biz[fr]);
          const float nn = tanh_c(xn + r*(acc[m][8+fr][reg] + bhn[fr]));
          const float hv = (1.0f - z)*nn + z*hold;
          h_out[(size_t)e*HR + db*64 + (((d6>>3) ^ (e&7))<<3) + (d6&7)] = f2b(hv);
          if (SCORE) sp += hv * atv[fr];
        }
      }
      if (SCORE){
        sp += __shfl_xor(sp, 1);
        sp += __shfl_xor(sp, 2);
        sp += __shfl_xor(sp, 4);
        sp += __shfl_xor(sp, 8);
        if (tx == 0 && e < N_EDGES) a_buf[e*NHEAD + db] = sp;   // unique writer
      }
    }
  }
}

// ---------------- score finalize: leaky-relu + segment max ----------------
__launch_bounds__(256)
__global__ void score2_kernel(const int* __restrict__ idx,
                              float* __restrict__ a_buf,
                              unsigned int* __restrict__ mmax)
{
  const int flat = blockIdx.x*256 + threadIdx.x;
  const int e = flat >> 3, h = flat & 7;
  const float s = a_buf[flat];
  const float a = s > 0.f ? s : 0.01f*s;
  a_buf[flat] = a;
  const int dst = idx[e*WALK + 3];
  union{float f; unsigned u;} x; x.f = a;
  const unsigned key = (x.u & 0x80000000u) ? ~x.u : (x.u | 0x80000000u);
  atomicMax(&mmax[dst*NHEAD + h], key);
}

// ---------------- exp(a-m) + segment sum ----------------
__launch_bounds__(256)
__global__ void ea_kernel(const int* __restrict__ idx,
                          float* __restrict__ a_buf,
                          const unsigned int* __restrict__ mmax,
                          float* __restrict__ ssum)
{
  const int flat = blockIdx.x*256 + threadIdx.x;
  const int e = flat >> 3, h = flat & 7;
  const int dst = idx[e*WALK + 3];
  const unsigned key = mmax[dst*NHEAD + h];
  union{float f; unsigned u;} x;
  x.u = (key & 0x80000000u) ? (key & 0x7FFFFFFFu) : ~key;
  const float ea = __expf(a_buf[flat] - x.f);
  a_buf[flat] = ea;
  atomicAdd(&ssum[dst*NHEAD + h], ea);
}

// ---------------- z[e] = (hT[e]*alpha) @ Wemb.T ; zacc[dst] += z[e] -------------------
// alpha computed inline: alpha = ea[e,h] / ssum[dst,h]  (alpha_kernel folded in)
__launch_bounds__(256)
__global__ void z_kernel(const unsigned short* __restrict__ hT,
                         const int* __restrict__ idx,
                         const float* __restrict__ ea_buf,
                         const float* __restrict__ ssum,
                         const unsigned short* __restrict__ WembP,
                         float* __restrict__ zacc)
{
  __shared__ __align__(16) char zs[40960];  // Az 32768 + Bz 8192
  char* Az = zs;
  char* Bz = zs + 32768;
  const int tid = threadIdx.x;
  const int lane = tid & 63;
  const int w = tid >> 6;
  const int e0 = blockIdx.x * 256;

  int ej[8], dstj[8];
  #pragma unroll
  for (int j=0;j<8;++j){
    int e = e0 + ((j*256 + tid) >> 3);
    if (e > N_EDGES-1) e = N_EDGES-1;
    ej[j] = e;
    dstj[j] = idx[e*WALK + 3];
  }

  f32x4 acc[4][4];
  #pragma unroll
  for (int m=0;m<4;++m)
    #pragma unroll
    for (int f=0;f<4;++f) acc[m][f] = (f32x4)(0.f);

  auto readFrag = [&](const char* base, int row, int kk)->bf16x8{
    const int chunk = (kk<<2) + (lane>>4);
    return *reinterpret_cast<const bf16x8*>(base + (row<<7) + ((chunk ^ (row&7))<<4));
  };

  #pragma unroll 1
  for (int kt=0; kt<8; ++kt){
    __syncthreads();
    #pragma unroll
    for (int j=0;j<8;++j){
      const int flat = j*256 + tid;
      const int e = ej[j];
      const u16x8 hv = *reinterpret_cast<const u16x8*>(hT + (size_t)e*HR + kt*64 + (flat&7)*8);
      const float al = ea_buf[e*NHEAD + kt] / ssum[dstj[j]*NHEAD + kt];
      union { bf16x8 v; unsigned short s[8]; } o;
      #pragma unroll
      for (int i=0;i<8;++i) o.s[i] = f2b(b2f(hv[i]) * al);
      *reinterpret_cast<bf16x8*>(Az + flat*16) = o.v;
    }
    #pragma unroll
    for (int j=0;j<2;++j){
      const int flat = j*256 + tid;
      const int row = flat >> 3, c = flat & 7;
      gload16(WembP + ((size_t)row*HR + kt*64 + c*8), Bz + ((j*256 + w*64)<<4));
    }
    __syncthreads();
    #pragma unroll
    for (int kk=0; kk<2; ++kk){
      bf16x8 a_[4];
      #pragma unroll
      for (int mf=0; mf<4; ++mf)
        a_[mf] = readFrag(Az, w*64 + mf*16 + (lane&15), kk);
      #pragma unroll
      for (int nf=0; nf<4; ++nf){
        const bf16x8 b_ = readFrag(Bz, nf*16 + (lane&15), kk);
        #pragma unroll
        for (int mf=0; mf<4; ++mf)
          acc[mf][nf] = mfma16(a_[mf], b_, acc[mf][nf]);
      }
    }
  }

  #pragma unroll
  for (int mf=0; mf<4; ++mf){
    #pragma unroll
    for (int reg=0; reg<4; ++reg){
      const int row = w*64 + mf*16 + ((lane>>4)<<2) + reg;
      const int e = e0 + row;
      if (e < N_EDGES){
        const int dst = idx[e*WALK + 3];
        #pragma unroll
        for (int nf=0; nf<4; ++nf){
          const int o = nf*16 + (lane&15);
          atomicAdd(&zacc[(size_t)dst*64 + o], acc[mf][nf][reg]);
        }
      }
    }
  }
}

// ---------------- out = (zacc + b_emb) @ W_last.T + b_last ----------------
__launch_bounds__(256)
__global__ void out2_kernel(const float* __restrict__ zacc,
                            const float* __restrict__ b_emb,
                            const float* __restrict__ W_last,
                            const float* __restrict__ b_last,
                            float* __restrict__ out)
{
  const int flat = blockIdx.x*256 + threadIdx.x;
  if (flat >= N_NODES*OUTD) return;
  const int n = flat >> 4, o = flat & 15;
  float s = b_last[o];
  const float* zr = &zacc[(size_t)n*64];
  const float* wl = &W_last[o*64];
  #pragma unroll
  for (int k=0;k<64;++k) s += (zr[k] + b_emb[k]) * wl[k];
  out[(size_t)n*OUTD + o] = s;
}

// ---------------- launch ----------------
extern "C" void kernel_launch(void* const* d_in, const int* in_sizes, int n_in,
                              void* d_out, int out_size, void* d_ws, size_t ws_size,
                              hipStream_t stream)
{
  (void)in_sizes; (void)n_in; (void)out_size; (void)ws_size;
  const float* x      = (const float*)d_in[0];
  const float* W_mlp  = (const float*)d_in[1];
  const float* b_mlp  = (const float*)d_in[2];
  const float* W_ih   = (const float*)d_in[3];
  const float* W_hh   = (const float*)d_in[4];
  const float* b_ih   = (const float*)d_in[5];
  const float* b_hh   = (const float*)d_in[6];
  const float* attn   = (const float*)d_in[7];
  const float* W_emb  = (const float*)d_in[8];
  const float* b_emb  = (const float*)d_in[9];
  const float* W_last = (const float*)d_in[10];
  const float* b_last = (const float*)d_in[11];
  const int*   idx    = (const int*)d_in[12];
  float* out = (float*)d_out;

  char* ws = (char*)d_ws;
  unsigned short* WhhP   = (unsigned short*)(ws + 0);            //   1,572,864
  unsigned short* WihP   = (unsigned short*)(ws + 1572864);      //     196,608
  unsigned short* WembP  = (unsigned short*)(ws + 1769472);      //      65,536
  unsigned short* emb_bf = (unsigned short*)(ws + 1835008);      //   2,560,000
  unsigned short* xnP    = (unsigned short*)(ws + 4395008);      //  20,480,000
  float*          a_buf  = (float*)(ws + 24875008);              //   3,200,000
  unsigned int*   mmax   = (unsigned int*)(ws + 28075008);       //     640,000
  float*          ssum   = (float*)(ws + 28715008);              //     640,000
  float*          zacc   = (float*)(ws + 29355008);              //   5,120,000
  unsigned short* h_a    = (unsigned short*)(ws + 34475008);     // 102,400,000
  unsigned short* h_b    = (unsigned short*)(ws + 136875008);    // 102,400,000
  unsigned short* h1n    = h_b;  // alias: h1n dead before gru step 2 writes h_b
  // total = 239,275,008 B

  // zero a_buf + mmax + ssum + zacc (contiguous 9.6 MB)
  hipMemsetAsync(a_buf, 0, 9600000, stream);

  prep_kernel<<<3072, 256, 0, stream>>>(W_hh, W_ih, W_emb, WhhP, WihP, WembP);
  emb_kernel<<<N_NODES/4, 256, 0, stream>>>(x, W_mlp, b_mlp, emb_bf);

  dim3 xgrid((N_NODES + 127)/128, 8);   // 157 x 8
  xg_kernel<<<xgrid, 256, 0, stream>>>(emb_bf, WihP, b_ih, b_hh, xnP, h1n);

  const int NWG = 782*8;  // 6256 blocks: 782 edge-tiles x 8 d-blocks
  gru_mfma<1,false><<<NWG, 256, 0, stream>>>(emb_bf, idx, h1n, h_a, WhhP, WihP, xnP, b_ih, b_hh, attn, a_buf);
  gru_mfma<2,false><<<NWG, 256, 0, stream>>>(emb_bf, idx, h_a, h_b, WhhP, WihP, xnP, b_ih, b_hh, attn, a_buf);
  gru_mfma<3,true ><<<NWG, 256, 0, stream>>>(emb_bf, idx, h_b, h_a, WhhP, WihP, xnP, b_ih, b_hh, attn, a_buf);
  // hT (swizzled) in h_a; raw scores in a_buf

  score2_kernel<<<N_EDGES*NHEAD/256, 256, 0, stream>>>(idx, a_buf, mmax);
  ea_kernel<<<N_EDGES*NHEAD/256, 256, 0, stream>>>(idx, a_buf, mmax, ssum);
  z_kernel<<<391, 256, 0, stream>>>(h_a, idx, a_buf, ssum, WembP, zacc);
  out2_kernel<<<(N_NODES*OUTD+255)/256, 256, 0, stream>>>(zacc, b_emb, W_last, b_last, out);
}